// Round 4
// baseline (12887.010 us; speedup 1.0000x reference)
//
#include <hip/hip_runtime.h>

#define SS 4096
#define LL 16
#define HD 512
#define ECD 128
#define HHD 256

typedef __attribute__((ext_vector_type(8))) short short8;
typedef __attribute__((ext_vector_type(4))) float float4v;
typedef _Float16 half2v __attribute__((ext_vector_type(2)));

__device__ __forceinline__ float bf2f(unsigned short u){
  union { unsigned int i; float f; } v; v.i = ((unsigned int)u) << 16; return v.f;
}
__device__ __forceinline__ unsigned short f2bf(float f){
  union { float f; unsigned int i; } v; v.f = f;
  unsigned int u = v.i;
  unsigned int r = (u + 0x7fffu + ((u >> 16) & 1u)) >> 16;
  return (unsigned short)r;
}
__device__ __forceinline__ float sigf(float x){ return 1.f / (1.f + __expf(-x)); }
__device__ __forceinline__ float tanh_f(float x){
  float e = __expf(2.f * x);
  return 1.f - 2.f / (e + 1.f);
}
__device__ __forceinline__ float fdot2u(unsigned int a, unsigned int b, float c){
  half2v ha = __builtin_bit_cast(half2v, a);
  half2v hb = __builtin_bit_cast(half2v, b);
#if __has_builtin(__builtin_amdgcn_fdot2)
  return __builtin_amdgcn_fdot2(ha, hb, c, false);
#else
  return c + (float)ha[0]*(float)hb[0] + (float)ha[1]*(float)hb[1];
#endif
}
__device__ __forceinline__ unsigned int packf16(float lo, float hi){
  half2v h; h[0] = (_Float16)lo; h[1] = (_Float16)hi;
  return __builtin_bit_cast(unsigned int, h);
}
__device__ __forceinline__ bool badf(float x){ return !(fabsf(x) < 1e30f); }

// pack 8 f32 -> 8 bf16 (as int4) for LDS staging
__device__ __forceinline__ int4 cvt8(const float* __restrict__ s){
  union { unsigned short u[8]; int4 v; } pk;
#pragma unroll
  for (int i = 0; i < 8; ++i) pk.u[i] = f2bf(s[i]);
  return pk.v;
}

// ---------------- prep: xUb[c][n] = char_emb[c].Wih_c[n] + bih_c[n] + bhh_c[n]  (bf16 out)
__global__ void prep_xu_k(const float* __restrict__ char_emb,
                          const float* __restrict__ Wih_c,
                          const float* __restrict__ bih_c,
                          const float* __restrict__ bhh_c,
                          unsigned short* __restrict__ xUb)
{
  int idx = blockIdx.x * 256 + threadIdx.x;   // 512 * 2048
  int c = idx >> 11, n = idx & 2047;
  const float* ce = char_emb + (size_t)c * ECD;
  const float* wr = Wih_c + (size_t)n * ECD;
  float acc = bih_c[n] + bhh_c[n];
  for (int k = 0; k < ECD; k += 4) {
    float4 a = *(const float4*)(ce + k);
    float4 b = *(const float4*)(wr + k);
    acc += a.x*b.x + a.y*b.y + a.z*b.z + a.w*b.w;
  }
  xUb[idx] = f2bf(acc);
}

// ---------------- prep: h0 = prefix_emb[feat_seq] (bf16), c0 = 0 (bf16)
__global__ void prep_h0c0_k(const float* __restrict__ prefix_emb,
                            const int* __restrict__ feat_seq,
                            unsigned short* __restrict__ h0,
                            unsigned short* __restrict__ c0)
{
  int idx = blockIdx.x * 256 + threadIdx.x;  // 4096*512
  int s = idx >> 9, j = idx & 511;
  h0[idx] = f2bf(prefix_emb[(size_t)feat_seq[s] * HD + j]);
  c0[idx] = 0;
}

// ---------------- prep: pack Whh_{f,b} (f32 in) to per-thread f16x2; biases; zero flags/hx/diag
__global__ void prep_scanw_k(const float* __restrict__ Whh_f,
                             const float* __restrict__ Whh_b,
                             const float* __restrict__ bih_f,
                             const float* __restrict__ bhh_f,
                             const float* __restrict__ bih_b,
                             const float* __restrict__ bhh_b,
                             unsigned int* __restrict__ Wpk,
                             float* __restrict__ biasbuf,
                             unsigned int* __restrict__ hx,
                             int* __restrict__ flags,
                             int* __restrict__ diag)
{
  int idx = blockIdx.x * 256 + threadIdx.x;  // 2*4*512*64 = 262144
  int d     = idx & 63;
  int tid   = (idx >> 6) & 511;
  int chunk = (idx >> 15) & 3;
  int dir   = (idx >> 17) & 1;
  int gate_local = tid >> 1;
  int gt = gate_local >> 6, hc = gate_local & 63;
  int hcol = chunk * 64 + hc;
  int grow = gt * 256 + hcol;
  int kbase = (tid & 1) * 128;
  int k = kbase + 2 * d;
  const float* W = dir ? Whh_b : Whh_f;  // [1024,256] f32
  Wpk[idx] = packf16(W[(size_t)grow * HHD + k], W[(size_t)grow * HHD + k + 1]);
  if (idx < 2048) {
    int dr = idx >> 10, g = idx & 1023;
    biasbuf[idx] = dr ? (bih_b[g] + bhh_b[g]) : (bih_f[g] + bhh_f[g]);
  }
  if (idx < 512) hx[idx] = 0u;
  if (idx < 128) flags[idx] = 0;
  if (idx == 0) diag[0] = 0;
}

// ---------------- fused char-step: gates = h_in @ Whh_c^T (MFMA), then LSTM cell epilogue
// grid: (512/32 = 16 n-tiles of 32 h-cols x 4 gates, 4096/128 = 32 m-tiles)
__global__ __launch_bounds__(256) void gemm_char_k(
    const unsigned short* __restrict__ hin,   // [4096,512] bf16
    const float* __restrict__ Whh,            // [2048,512] f32
    const unsigned short* __restrict__ xUb,   // [512,2048] bf16
    const int* __restrict__ chars,
    const int* __restrict__ lens,
    int t,
    unsigned short* __restrict__ hout,        // [4096,512] bf16
    unsigned short* __restrict__ cb,          // [4096,512] bf16 (in/out)
    int* __restrict__ diag)
{
  __shared__ __align__(16) unsigned short As[128 * 32];
  __shared__ __align__(16) unsigned short Bs[128 * 32];
  __shared__ __align__(16) unsigned short gates[128 * 136];
  const int tid = threadIdx.x;
  const int m0 = blockIdx.y * 128;
  const int n0h = blockIdx.x * 32;            // base h-column of this tile
  const int wave = tid >> 6;
  const int lane = tid & 63;
  const int wm = (wave >> 1) * 64;
  const int wn = (wave & 1) * 64;
  float4v z = {0.f, 0.f, 0.f, 0.f};
  float4v acc[4][4];
#pragma unroll
  for (int i = 0; i < 4; ++i)
#pragma unroll
    for (int j = 0; j < 4; ++j) acc[i][j] = z;

  for (int k0 = 0; k0 < 512; k0 += 32) {
    __syncthreads();
#pragma unroll
    for (int i = 0; i < 2; ++i) {
      int chunk = tid * 2 + i;           // 0..511
      int row = chunk >> 2;              // 0..127
      int k8 = (chunk & 3) * 8;
      int4 av = *(const int4*)(hin + (size_t)(m0 + row) * 512 + k0 + k8);
      *(int4*)(As + row * 32 + k8) = av;
      // B row remap: local row r -> gate (r>>5), h-col n0h + (r&31)
      int br = (row >> 5) * 512 + n0h + (row & 31);
      *(int4*)(Bs + row * 32 + k8) = cvt8(Whh + (size_t)br * 512 + k0 + k8);
    }
    __syncthreads();
    short8 af[4], bfr[4];
    const int kq = (lane >> 4) * 8;
#pragma unroll
    for (int i = 0; i < 4; ++i) {
      af[i]  = *(const short8*)(As + (wm + i * 16 + (lane & 15)) * 32 + kq);
      bfr[i] = *(const short8*)(Bs + (wn + i * 16 + (lane & 15)) * 32 + kq);
    }
#pragma unroll
    for (int i = 0; i < 4; ++i)
#pragma unroll
      for (int j = 0; j < 4; ++j)
        acc[i][j] = __builtin_amdgcn_mfma_f32_16x16x32_bf16(af[i], bfr[j], acc[i][j], 0, 0, 0);
  }
  __syncthreads();
  // dump C tile to LDS (bf16), C/D layout: col=lane&15, row=(lane>>4)*4+reg (m89-verified)
#pragma unroll
  for (int i = 0; i < 4; ++i)
#pragma unroll
    for (int j = 0; j < 4; ++j)
#pragma unroll
      for (int r = 0; r < 4; ++r) {
        int row = wm + i * 16 + (lane >> 4) * 4 + r;
        int col = wn + j * 16 + (lane & 15);
        gates[row * 136 + col] = f2bf(acc[i][j][r]);
      }
  __syncthreads();
  // cell epilogue: 128 rows x 32 h-cols = 4096 cells, 16 per thread
#pragma unroll
  for (int e = 0; e < 16; ++e) {
    int idx = e * 256 + tid;
    int r = idx >> 5, hc = idx & 31;
    int s = m0 + r;
    int col = n0h + hc;
    if (t < lens[s]) {
      int cid = chars[s * LL + t];
      size_t xb = (size_t)cid * 2048 + col;
      float gi = bf2f(gates[r * 136 + hc])      + bf2f(xUb[xb]);
      float gf = bf2f(gates[r * 136 + 32 + hc]) + bf2f(xUb[xb + 512]);
      float gg = bf2f(gates[r * 136 + 64 + hc]) + bf2f(xUb[xb + 1024]);
      float go = bf2f(gates[r * 136 + 96 + hc]) + bf2f(xUb[xb + 1536]);
      if (badf(gi + gf + gg + go)) atomicOr(diag, 1);
      float cc = sigf(gf) * bf2f(cb[(size_t)s * 512 + col]) + sigf(gi) * tanh_f(gg);
      cb[(size_t)s * 512 + col] = f2bf(cc);
      hout[(size_t)s * 512 + col] = f2bf(sigf(go) * tanh_f(cc));
    } else {
      hout[(size_t)s * 512 + col] = hin[(size_t)s * 512 + col];
    }
  }
}

// ---------------- P GEMM: P[M=4096, N=1024](bf16) = [word_emb[wseq] f32 | h bf16] @ Wih^T(f32)
__global__ __launch_bounds__(256) void gemm_gather_nt_k(
    const float* __restrict__ wemb,
    const int* __restrict__ wseq,
    const unsigned short* __restrict__ hbuf,
    const float* __restrict__ B,              // [1024,1024] f32
    unsigned short* __restrict__ P)           // [4096,1024] bf16
{
  __shared__ __align__(16) unsigned short As[128 * 32];
  __shared__ __align__(16) unsigned short Bs[128 * 32];
  const int tid = threadIdx.x;
  const int m0 = blockIdx.y * 128;
  const int n0 = blockIdx.x * 128;
  const int wave = tid >> 6;
  const int lane = tid & 63;
  const int wm = (wave >> 1) * 64;
  const int wn = (wave & 1) * 64;
  float4v z = {0.f, 0.f, 0.f, 0.f};
  float4v acc[4][4];
#pragma unroll
  for (int i = 0; i < 4; ++i)
#pragma unroll
    for (int j = 0; j < 4; ++j) acc[i][j] = z;

  for (int k0 = 0; k0 < 1024; k0 += 32) {
    __syncthreads();
#pragma unroll
    for (int i = 0; i < 2; ++i) {
      int chunk = tid * 2 + i;
      int row = chunk >> 2;
      int k8 = (chunk & 3) * 8;
      int arow = m0 + row;
      int acol = k0 + k8;
      if (acol < 512) {
        *(int4*)(As + row * 32 + k8) = cvt8(wemb + (size_t)wseq[arow] * 512 + acol);
      } else {
        int4 av = *(const int4*)(hbuf + (size_t)arow * 512 + (acol - 512));
        *(int4*)(As + row * 32 + k8) = av;
      }
      *(int4*)(Bs + row * 32 + k8) = cvt8(B + (size_t)(n0 + row) * 1024 + k0 + k8);
    }
    __syncthreads();
    short8 af[4], bfr[4];
    const int kq = (lane >> 4) * 8;
#pragma unroll
    for (int i = 0; i < 4; ++i) {
      af[i]  = *(const short8*)(As + (wm + i * 16 + (lane & 15)) * 32 + kq);
      bfr[i] = *(const short8*)(Bs + (wn + i * 16 + (lane & 15)) * 32 + kq);
    }
#pragma unroll
    for (int i = 0; i < 4; ++i)
#pragma unroll
      for (int j = 0; j < 4; ++j)
        acc[i][j] = __builtin_amdgcn_mfma_f32_16x16x32_bf16(af[i], bfr[j], acc[i][j], 0, 0, 0);
  }
#pragma unroll
  for (int i = 0; i < 4; ++i)
#pragma unroll
    for (int j = 0; j < 4; ++j)
#pragma unroll
      for (int r = 0; r < 4; ++r) {
        int row = m0 + wm + i * 16 + (lane >> 4) * 4 + r;
        int col = n0 + wn + j * 16 + (lane & 15);
        P[(size_t)row * 1024 + col] = f2bf(acc[i][j][r]);
      }
}

// ---------------- persistent bidirectional scan (dirsel<0: 8 WGs both dirs; else 4 WGs one dir)
__global__ __launch_bounds__(512) void scan_k(
    const unsigned short* __restrict__ P_f,   // [4096,1024] bf16
    const unsigned short* __restrict__ P_b,
    const unsigned int* __restrict__ Wpk,
    const float* __restrict__ biasbuf,        // [2][1024] f32
    unsigned short* __restrict__ out_f,       // [4096,256] bf16
    unsigned short* __restrict__ out_b,
    unsigned int* hx, int* flags, int* diag, int dirsel)
{
  int dir, chunk;
  if (dirsel < 0) { dir = blockIdx.x >> 2; chunk = blockIdx.x & 3; }
  else            { dir = dirsel;          chunk = blockIdx.x; }
  const int tid = threadIdx.x;
  const int gate_local = tid >> 1, khalf = tid & 1;
  const int gt = gate_local >> 6, hc = gate_local & 63;
  const int hcol = chunk * 64 + hc, grow = gt * 256 + hcol;

  __shared__ __align__(16) float g_lds[256];
  __shared__ __align__(16) float c_lds[64];
  __shared__ __align__(16) float h_stage[64];
  __shared__ __align__(16) unsigned int hp[2][128];

  unsigned int w[64];
  {
    const uint4* wp = (const uint4*)(Wpk + ((size_t)((dir * 4 + chunk) * 512 + tid)) * 64);
#pragma unroll
    for (int q = 0; q < 16; ++q) {
      uint4 v = wp[q];
      w[4 * q + 0] = v.x; w[4 * q + 1] = v.y; w[4 * q + 2] = v.z; w[4 * q + 3] = v.w;
    }
  }
  const float bg = khalf ? 0.f : biasbuf[dir * 1024 + grow];
  const unsigned short* P = dir ? P_b : P_f;
  unsigned short* out = dir ? out_b : out_f;
  unsigned int* hxd = hx + dir * 256;
  int* flg = flags + dir * 64;

  if (tid < 64) c_lds[tid] = 0.f;
  if (tid < 128) hp[0][tid] = 0u;
  __syncthreads();

  for (int t = 0; t < 4096; ++t) {
    const int p = t & 1;
    const int srow = dir ? (4095 - t) : t;
    float acc = 0.f;
    const uint4* hb = (const uint4*)(&hp[p][khalf * 64]);
#pragma unroll
    for (int q = 0; q < 16; ++q) {
      uint4 hv = hb[q];
      acc = fdot2u(w[4 * q + 0], hv.x, acc);
      acc = fdot2u(w[4 * q + 1], hv.y, acc);
      acc = fdot2u(w[4 * q + 2], hv.z, acc);
      acc = fdot2u(w[4 * q + 3], hv.w, acc);
    }
    acc += __shfl_xor(acc, 1);
    if (!khalf) g_lds[gate_local] = acc + bg + bf2f(P[(size_t)srow * 1024 + grow]);
    __syncthreads();
    if (tid < 64) {
      float gi = g_lds[tid], gf = g_lds[64 + tid], gg = g_lds[128 + tid], go = g_lds[192 + tid];
      if (badf(gi + gf + gg + go)) atomicOr(diag, 2);
      float cc = sigf(gf) * c_lds[tid] + sigf(gi) * tanh_f(gg);
      float hh = sigf(go) * tanh_f(cc);
      c_lds[tid] = cc;
      h_stage[tid] = hh;
      out[(size_t)srow * HHD + chunk * 64 + tid] = f2bf(hh);
    }
    __syncthreads();
    if (t < 4095) {
      const int p2 = p ^ 1;
      if (tid < 32) {
        unsigned int pk = packf16(h_stage[2 * tid], h_stage[2 * tid + 1]);
        __hip_atomic_store(&hxd[p2 * 128 + chunk * 32 + tid], pk,
                           __ATOMIC_RELAXED, __HIP_MEMORY_SCOPE_AGENT);
      }
      __syncthreads();
      if (tid == 0) {
        __threadfence();
        __hip_atomic_store(&flg[chunk * 16], t + 1, __ATOMIC_RELEASE, __HIP_MEMORY_SCOPE_AGENT);
      }
      if (tid < 4) {
        while (__hip_atomic_load(&flg[tid * 16], __ATOMIC_ACQUIRE, __HIP_MEMORY_SCOPE_AGENT) < t + 1) {}
      }
      __syncthreads();
      if (tid < 128)
        hp[p2][tid] = __hip_atomic_load(&hxd[p2 * 128 + tid],
                                        __ATOMIC_ACQUIRE, __HIP_MEMORY_SCOPE_AGENT);
      __syncthreads();
    }
  }
}

// ---------------- heads: logits + log_softmax -> f32 out
__global__ __launch_bounds__(128) void head_k(
    const unsigned short* __restrict__ out_f, const unsigned short* __restrict__ out_b,
    const float* __restrict__ Wpos, const float* __restrict__ bpos,
    const float* __restrict__ Wner, const float* __restrict__ bner,
    float* __restrict__ dout, int* __restrict__ diag)
{
  const int s = blockIdx.x, tid = threadIdx.x;
  __shared__ __align__(16) float xv[512];
#pragma unroll
  for (int i = 0; i < 4; ++i) {
    int k = tid * 4 + i;
    xv[k] = (k < 256) ? bf2f(out_f[(size_t)s * 256 + k])
                      : bf2f(out_b[(size_t)s * 256 + (k - 256)]);
  }
  __syncthreads();
  float logit = 0.f;
  const int j = tid;
  if (j < 96) {
    const float* wr = (j < 64) ? (Wpos + (size_t)j * 512)
                               : (Wner + (size_t)(j - 64) * 512);
    float b = (j < 64) ? bpos[j] : bner[j - 64];
    float acc = 0.f;
    for (int k = 0; k < 512; k += 4) {
      float4 wv = *(const float4*)(wr + k);
      acc += xv[k] * wv.x + xv[k + 1] * wv.y + xv[k + 2] * wv.z + xv[k + 3] * wv.w;
    }
    logit = acc + b;
    if (badf(logit)) { atomicOr(diag, 4); logit = 0.f; }
  }
  if (j < 64) {
    float m = logit;
    for (int o = 32; o >= 1; o >>= 1) m = fmaxf(m, __shfl_xor(m, o));
    float e = __expf(logit - m), sum = e;
    for (int o = 32; o >= 1; o >>= 1) sum += __shfl_xor(sum, o);
    float v = logit - m - logf(sum);
    if (!(v > -1e30f && v < 1e30f)) v = -111.f;
    dout[(size_t)s * 64 + j] = v;
  } else if (j < 96) {
    float m = logit;
    for (int o = 16; o >= 1; o >>= 1) m = fmaxf(m, __shfl_xor(m, o, 32));
    float e = __expf(logit - m), sum = e;
    for (int o = 16; o >= 1; o >>= 1) sum += __shfl_xor(sum, o, 32);
    float v = logit - m - logf(sum);
    if (!(v > -1e30f && v < 1e30f)) v = -111.f;
    dout[262144 + (size_t)s * 32 + (j - 64)] = v;
  }
}

// ---------------- diagnostics: f32-dtype sniff + error-code emit (silent when healthy)
__global__ void diag_k(const float* __restrict__ ce,
                       int* __restrict__ diag,
                       float* __restrict__ dout)
{
  int cnt = 0;
  for (int i = 0; i < 64; ++i) {
    float x = ce[i];
    if (x == x && fabsf(x) < 100.f) cnt++;   // plausible for 0.05*randn f32
  }
  if (cnt < 48) diag[0] |= 8;
  int d = diag[0];
  if (d) dout[0] = 1000.f + 100.f * (float)d;
}

__global__ void wssmall_k(float* __restrict__ dout, int mb)
{
  dout[0] = 10000.f + (float)mb;
}

extern "C" void kernel_launch(void* const* d_in, const int* in_sizes, int n_in,
                              void* d_out, int out_size, void* d_ws, size_t ws_size,
                              hipStream_t stream) {
  const int*   word_seq  = (const int*)d_in[0];
  const int*   chars     = (const int*)d_in[1];
  const int*   char_lens = (const int*)d_in[2];
  const int*   feat_seq  = (const int*)d_in[3];
  const float* char_emb  = (const float*)d_in[4];
  const float* word_emb  = (const float*)d_in[5];
  const float* prefix_emb= (const float*)d_in[6];
  const float* Wih_c     = (const float*)d_in[7];
  const float* Whh_c     = (const float*)d_in[8];
  const float* bih_c     = (const float*)d_in[9];
  const float* bhh_c     = (const float*)d_in[10];
  const float* Wih_f     = (const float*)d_in[11];
  const float* Whh_f     = (const float*)d_in[12];
  const float* bih_f     = (const float*)d_in[13];
  const float* bhh_f     = (const float*)d_in[14];
  const float* Wih_b     = (const float*)d_in[15];
  const float* Whh_b     = (const float*)d_in[16];
  const float* bih_b     = (const float*)d_in[17];
  const float* bhh_b     = (const float*)d_in[18];
  const float* Wpos      = (const float*)d_in[19];
  const float* bpos      = (const float*)d_in[20];
  const float* Wner      = (const float*)d_in[21];
  const float* bner      = (const float*)d_in[22];
  float* dout = (float*)d_out;

  const size_t MB = 1048576;
  char* ws = (char*)d_ws;
  // small region
  int*            flags = (int*)(ws + 0);            // 512 B
  int*            diag  = (int*)(ws + 512);          // 512 B
  unsigned int*   hx    = (unsigned int*)(ws + 1024);// 2 KB
  float*          bias2 = (float*)(ws + 4096);       // 8 KB
  unsigned int*   Wpk   = (unsigned int*)(ws + 65536);// 1 MB
  // big region (phase-overlapped)
  unsigned short* hA    = (unsigned short*)(ws + 2 * MB);   // 4 MB [4096,512] bf16
  unsigned short* hB    = (unsigned short*)(ws + 6 * MB);   // 4 MB
  unsigned short* xUb   = (unsigned short*)(ws + 10 * MB);  // 2 MB [512,2048] bf16
  unsigned short* cb    = (unsigned short*)(ws + 12 * MB);  // 4 MB [4096,512] bf16 (ends 16MB)

  const size_t NEED_A = 21 * MB;   // parallel scans: P_f@6MB(8) + P_b@14MB(8) -> ends 22? see below
  const size_t NEED_B = 16 * MB;   // sequential scans: P@6MB(8) -> ends 14MB; out_f@14MB(2)

  if (ws_size >= NEED_A) {
    // Layout A: P_f at 6MB..14MB, P_b at 14MB..22MB?? -> cap: use 6..14 and 13..21 overlap-free:
    // P_f = 6MB (8MB), P_b = 13MB? P_b must not overlap P_f. Use P_f=6MB, P_b=ws+13*MB only if
    // 13MB>=14MB false -> keep simple: require 22MB when available.
    ;
  }

  // Decide layout: A needs 22MB (P_f 6..14, P_b 14..22). B needs 16MB.
  const size_t NEED_A2 = 22 * MB;
  unsigned short* P_f;
  unsigned short* P_b;
  unsigned short* out_f;
  unsigned short* out_b;
  int layoutA;
  if (ws_size >= NEED_A2) {
    layoutA = 1;
    P_f   = (unsigned short*)(ws + 6 * MB);    // over dead hB/xUb
    P_b   = (unsigned short*)(ws + 14 * MB);   // over dead cb + fresh
    out_f = (unsigned short*)(ws + 2 * MB);    // over dead hA
    out_b = (unsigned short*)(ws + 4 * MB);
  } else if (ws_size >= NEED_B) {
    layoutA = 0;
    P_f   = (unsigned short*)(ws + 6 * MB);    // shared P buffer
    P_b   = (unsigned short*)(ws + 6 * MB);
    out_f = (unsigned short*)(ws + 14 * MB);   // over dead cb tail
    out_b = (unsigned short*)(ws + 2 * MB);    // over dead hA (after P_b gemm)
  } else {
    wssmall_k<<<1, 1, 0, stream>>>(dout, (int)(ws_size >> 20));
    return;
  }

  prep_xu_k<<<(512 * 2048) / 256, 256, 0, stream>>>(char_emb, Wih_c, bih_c, bhh_c, xUb);
  prep_h0c0_k<<<(4096 * 512) / 256, 256, 0, stream>>>(prefix_emb, feat_seq, hA, cb);
  prep_scanw_k<<<(2 * 4 * 512 * 64) / 256, 256, 0, stream>>>(
      Whh_f, Whh_b, bih_f, bhh_f, bih_b, bhh_b, Wpk, bias2, hx, flags, diag);

  unsigned short* hcur = hA;
  unsigned short* hnxt = hB;
  for (int t = 0; t < 16; ++t) {
    gemm_char_k<<<dim3(16, 32), 256, 0, stream>>>(
        hcur, Whh_c, xUb, chars, char_lens, t, hnxt, cb, diag);
    unsigned short* tmp = hcur; hcur = hnxt; hnxt = tmp;
  }
  // after 16 swaps, final char features are in hA (hcur == hA)

  if (layoutA) {
    gemm_gather_nt_k<<<dim3(8, 32), 256, 0, stream>>>(word_emb, word_seq, hcur, Wih_f, P_f);
    gemm_gather_nt_k<<<dim3(8, 32), 256, 0, stream>>>(word_emb, word_seq, hcur, Wih_b, P_b);
    scan_k<<<8, 512, 0, stream>>>(P_f, P_b, Wpk, bias2, out_f, out_b, hx, flags, diag, -1);
  } else {
    gemm_gather_nt_k<<<dim3(8, 32), 256, 0, stream>>>(word_emb, word_seq, hcur, Wih_f, P_f);
    scan_k<<<4, 512, 0, stream>>>(P_f, P_b, Wpk, bias2, out_f, out_b, hx, flags, diag, 0);
    gemm_gather_nt_k<<<dim3(8, 32), 256, 0, stream>>>(word_emb, word_seq, hcur, Wih_b, P_b);
    scan_k<<<4, 512, 0, stream>>>(P_f, P_b, Wpk, bias2, out_f, out_b, hx, flags, diag, 1);
  }

  head_k<<<4096, 128, 0, stream>>>(out_f, out_b, Wpos, bpos, Wner, bner, dout, diag);

  diag_k<<<1, 1, 0, stream>>>(char_emb, diag, dout);
}

// Round 5
// 8061.326 us; speedup vs baseline: 1.5986x; 1.5986x over previous
//
#include <hip/hip_runtime.h>

#define SS 4096
#define LL 16
#define HD 512
#define ECD 128
#define HHD 256

typedef __attribute__((ext_vector_type(8))) short short8;
typedef __attribute__((ext_vector_type(4))) float float4v;
typedef _Float16 half2v __attribute__((ext_vector_type(2)));

__device__ __forceinline__ float bf2f(unsigned short u){
  union { unsigned int i; float f; } v; v.i = ((unsigned int)u) << 16; return v.f;
}
__device__ __forceinline__ unsigned short f2bf(float f){
  union { float f; unsigned int i; } v; v.f = f;
  unsigned int u = v.i;
  unsigned int r = (u + 0x7fffu + ((u >> 16) & 1u)) >> 16;
  return (unsigned short)r;
}
__device__ __forceinline__ unsigned short f2h(float x){
  _Float16 h = (_Float16)x;
  return __builtin_bit_cast(unsigned short, h);
}
__device__ __forceinline__ float sigf(float x){ return 1.f / (1.f + __expf(-x)); }
__device__ __forceinline__ float tanh_f(float x){
  float e = __expf(2.f * x);
  return 1.f - 2.f / (e + 1.f);
}
__device__ __forceinline__ float fdot2u(unsigned int a, unsigned int b, float c){
  half2v ha = __builtin_bit_cast(half2v, a);
  half2v hb = __builtin_bit_cast(half2v, b);
#if __has_builtin(__builtin_amdgcn_fdot2)
  return __builtin_amdgcn_fdot2(ha, hb, c, false);
#else
  return c + (float)ha[0]*(float)hb[0] + (float)ha[1]*(float)hb[1];
#endif
}
__device__ __forceinline__ unsigned int packf16(float lo, float hi){
  half2v h; h[0] = (_Float16)lo; h[1] = (_Float16)hi;
  return __builtin_bit_cast(unsigned int, h);
}
__device__ __forceinline__ bool badf(float x){ return !(fabsf(x) < 1e30f); }

// pack 8 f32 -> 8 bf16 (as int4) for LDS staging
__device__ __forceinline__ int4 cvt8(const float* __restrict__ s){
  union { unsigned short u[8]; int4 v; } pk;
#pragma unroll
  for (int i = 0; i < 8; ++i) pk.u[i] = f2bf(s[i]);
  return pk.v;
}

// ---------------- prep: xUb[c][n] = char_emb[c].Wih_c[n] + bih_c[n] + bhh_c[n]  (bf16 out)
__global__ void prep_xu_k(const float* __restrict__ char_emb,
                          const float* __restrict__ Wih_c,
                          const float* __restrict__ bih_c,
                          const float* __restrict__ bhh_c,
                          unsigned short* __restrict__ xUb)
{
  int idx = blockIdx.x * 256 + threadIdx.x;   // 512 * 2048
  int c = idx >> 11, n = idx & 2047;
  const float* ce = char_emb + (size_t)c * ECD;
  const float* wr = Wih_c + (size_t)n * ECD;
  float acc = bih_c[n] + bhh_c[n];
  for (int k = 0; k < ECD; k += 4) {
    float4 a = *(const float4*)(ce + k);
    float4 b = *(const float4*)(wr + k);
    acc += a.x*b.x + a.y*b.y + a.z*b.z + a.w*b.w;
  }
  xUb[idx] = f2bf(acc);
}

// ---------------- prep: h0 = prefix_emb[feat_seq] (bf16), c0 = 0 (bf16)
__global__ void prep_h0c0_k(const float* __restrict__ prefix_emb,
                            const int* __restrict__ feat_seq,
                            unsigned short* __restrict__ h0,
                            unsigned short* __restrict__ c0)
{
  int idx = blockIdx.x * 256 + threadIdx.x;  // 4096*512
  int s = idx >> 9, j = idx & 511;
  h0[idx] = f2bf(prefix_emb[(size_t)feat_seq[s] * HD + j]);
  c0[idx] = 0;
}

// ---------------- prep: pack Whh_{f,b} (f32 in) to per-thread f16x2; biases; zero hx/diag
__global__ void prep_scanw_k(const float* __restrict__ Whh_f,
                             const float* __restrict__ Whh_b,
                             const float* __restrict__ bih_f,
                             const float* __restrict__ bhh_f,
                             const float* __restrict__ bih_b,
                             const float* __restrict__ bhh_b,
                             unsigned int* __restrict__ Wpk,
                             float* __restrict__ biasbuf,
                             unsigned int* __restrict__ hx,
                             int* __restrict__ diag)
{
  int idx = blockIdx.x * 256 + threadIdx.x;  // 2*4*512*64 = 262144
  int d     = idx & 63;
  int tid   = (idx >> 6) & 511;
  int chunk = (idx >> 15) & 3;
  int dir   = (idx >> 17) & 1;
  int gate_local = tid >> 1;
  int gt = gate_local >> 6, hc = gate_local & 63;
  int hcol = chunk * 64 + hc;
  int grow = gt * 256 + hcol;
  int kbase = (tid & 1) * 128;
  int k = kbase + 2 * d;
  const float* W = dir ? Whh_b : Whh_f;  // [1024,256] f32
  Wpk[idx] = packf16(W[(size_t)grow * HHD + k], W[(size_t)grow * HHD + k + 1]);
  if (idx < 2048) {
    int dr = idx >> 10, g = idx & 1023;
    biasbuf[idx] = dr ? (bih_b[g] + bhh_b[g]) : (bih_f[g] + bhh_f[g]);
  }
  // hx: 2 dirs x 2 slots x 256 tagged words; tag0|f16(0) == 0 is the valid t=0 state
  if (idx < 1024) hx[idx] = 0u;
  if (idx == 0) diag[0] = 0;
}

// ---------------- fused char-step: gates = h_in @ Whh_c^T (MFMA), then LSTM cell epilogue
__global__ __launch_bounds__(256) void gemm_char_k(
    const unsigned short* __restrict__ hin,   // [4096,512] bf16
    const float* __restrict__ Whh,            // [2048,512] f32
    const unsigned short* __restrict__ xUb,   // [512,2048] bf16
    const int* __restrict__ chars,
    const int* __restrict__ lens,
    int t,
    unsigned short* __restrict__ hout,        // [4096,512] bf16
    unsigned short* __restrict__ cb,          // [4096,512] bf16 (in/out)
    int* __restrict__ diag)
{
  __shared__ __align__(16) unsigned short As[128 * 32];
  __shared__ __align__(16) unsigned short Bs[128 * 32];
  __shared__ __align__(16) unsigned short gates[128 * 136];
  const int tid = threadIdx.x;
  const int m0 = blockIdx.y * 128;
  const int n0h = blockIdx.x * 32;            // base h-column of this tile
  const int wave = tid >> 6;
  const int lane = tid & 63;
  const int wm = (wave >> 1) * 64;
  const int wn = (wave & 1) * 64;
  float4v z = {0.f, 0.f, 0.f, 0.f};
  float4v acc[4][4];
#pragma unroll
  for (int i = 0; i < 4; ++i)
#pragma unroll
    for (int j = 0; j < 4; ++j) acc[i][j] = z;

  for (int k0 = 0; k0 < 512; k0 += 32) {
    __syncthreads();
#pragma unroll
    for (int i = 0; i < 2; ++i) {
      int chunk = tid * 2 + i;           // 0..511
      int row = chunk >> 2;              // 0..127
      int k8 = (chunk & 3) * 8;
      int4 av = *(const int4*)(hin + (size_t)(m0 + row) * 512 + k0 + k8);
      *(int4*)(As + row * 32 + k8) = av;
      int br = (row >> 5) * 512 + n0h + (row & 31);
      *(int4*)(Bs + row * 32 + k8) = cvt8(Whh + (size_t)br * 512 + k0 + k8);
    }
    __syncthreads();
    short8 af[4], bfr[4];
    const int kq = (lane >> 4) * 8;
#pragma unroll
    for (int i = 0; i < 4; ++i) {
      af[i]  = *(const short8*)(As + (wm + i * 16 + (lane & 15)) * 32 + kq);
      bfr[i] = *(const short8*)(Bs + (wn + i * 16 + (lane & 15)) * 32 + kq);
    }
#pragma unroll
    for (int i = 0; i < 4; ++i)
#pragma unroll
      for (int j = 0; j < 4; ++j)
        acc[i][j] = __builtin_amdgcn_mfma_f32_16x16x32_bf16(af[i], bfr[j], acc[i][j], 0, 0, 0);
  }
  __syncthreads();
#pragma unroll
  for (int i = 0; i < 4; ++i)
#pragma unroll
    for (int j = 0; j < 4; ++j)
#pragma unroll
      for (int r = 0; r < 4; ++r) {
        int row = wm + i * 16 + (lane >> 4) * 4 + r;
        int col = wn + j * 16 + (lane & 15);
        gates[row * 136 + col] = f2bf(acc[i][j][r]);
      }
  __syncthreads();
#pragma unroll
  for (int e = 0; e < 16; ++e) {
    int idx = e * 256 + tid;
    int r = idx >> 5, hc = idx & 31;
    int s = m0 + r;
    int col = n0h + hc;
    if (t < lens[s]) {
      int cid = chars[s * LL + t];
      size_t xb = (size_t)cid * 2048 + col;
      float gi = bf2f(gates[r * 136 + hc])      + bf2f(xUb[xb]);
      float gf = bf2f(gates[r * 136 + 32 + hc]) + bf2f(xUb[xb + 512]);
      float gg = bf2f(gates[r * 136 + 64 + hc]) + bf2f(xUb[xb + 1024]);
      float go = bf2f(gates[r * 136 + 96 + hc]) + bf2f(xUb[xb + 1536]);
      if (badf(gi + gf + gg + go)) atomicOr(diag, 1);
      float cc = sigf(gf) * bf2f(cb[(size_t)s * 512 + col]) + sigf(gi) * tanh_f(gg);
      cb[(size_t)s * 512 + col] = f2bf(cc);
      hout[(size_t)s * 512 + col] = f2bf(sigf(go) * tanh_f(cc));
    } else {
      hout[(size_t)s * 512 + col] = hin[(size_t)s * 512 + col];
    }
  }
}

// ---------------- P GEMM: P[M=4096, N=1024](bf16) = [word_emb[wseq] f32 | h bf16] @ Wih^T(f32)
__global__ __launch_bounds__(256) void gemm_gather_nt_k(
    const float* __restrict__ wemb,
    const int* __restrict__ wseq,
    const unsigned short* __restrict__ hbuf,
    const float* __restrict__ B,              // [1024,1024] f32
    unsigned short* __restrict__ P)           // [4096,1024] bf16
{
  __shared__ __align__(16) unsigned short As[128 * 32];
  __shared__ __align__(16) unsigned short Bs[128 * 32];
  const int tid = threadIdx.x;
  const int m0 = blockIdx.y * 128;
  const int n0 = blockIdx.x * 128;
  const int wave = tid >> 6;
  const int lane = tid & 63;
  const int wm = (wave >> 1) * 64;
  const int wn = (wave & 1) * 64;
  float4v z = {0.f, 0.f, 0.f, 0.f};
  float4v acc[4][4];
#pragma unroll
  for (int i = 0; i < 4; ++i)
#pragma unroll
    for (int j = 0; j < 4; ++j) acc[i][j] = z;

  for (int k0 = 0; k0 < 1024; k0 += 32) {
    __syncthreads();
#pragma unroll
    for (int i = 0; i < 2; ++i) {
      int chunk = tid * 2 + i;
      int row = chunk >> 2;
      int k8 = (chunk & 3) * 8;
      int arow = m0 + row;
      int acol = k0 + k8;
      if (acol < 512) {
        *(int4*)(As + row * 32 + k8) = cvt8(wemb + (size_t)wseq[arow] * 512 + acol);
      } else {
        int4 av = *(const int4*)(hbuf + (size_t)arow * 512 + (acol - 512));
        *(int4*)(As + row * 32 + k8) = av;
      }
      *(int4*)(Bs + row * 32 + k8) = cvt8(B + (size_t)(n0 + row) * 1024 + k0 + k8);
    }
    __syncthreads();
    short8 af[4], bfr[4];
    const int kq = (lane >> 4) * 8;
#pragma unroll
    for (int i = 0; i < 4; ++i) {
      af[i]  = *(const short8*)(As + (wm + i * 16 + (lane & 15)) * 32 + kq);
      bfr[i] = *(const short8*)(Bs + (wn + i * 16 + (lane & 15)) * 32 + kq);
    }
#pragma unroll
    for (int i = 0; i < 4; ++i)
#pragma unroll
      for (int j = 0; j < 4; ++j)
        acc[i][j] = __builtin_amdgcn_mfma_f32_16x16x32_bf16(af[i], bfr[j], acc[i][j], 0, 0, 0);
  }
#pragma unroll
  for (int i = 0; i < 4; ++i)
#pragma unroll
    for (int j = 0; j < 4; ++j)
#pragma unroll
      for (int r = 0; r < 4; ++r) {
        int row = m0 + wm + i * 16 + (lane >> 4) * 4 + r;
        int col = n0 + wn + j * 16 + (lane & 15);
        P[(size_t)row * 1024 + col] = f2bf(acc[i][j][r]);
      }
}

// ---------------- persistent bidirectional scan, tagged self-validating h exchange
// hx layout: [dir][slot=t&1][256] u32, word = (tag16 << 16) | f16(h). No fences/flags.
__global__ __launch_bounds__(512) void scan_k(
    const unsigned short* __restrict__ P_f,   // [4096,1024] bf16
    const unsigned short* __restrict__ P_b,
    const unsigned int* __restrict__ Wpk,
    const float* __restrict__ biasbuf,        // [2][1024] f32
    unsigned short* __restrict__ out_f,       // [4096,256] bf16
    unsigned short* __restrict__ out_b,
    unsigned int* hx, int* diag, int dirsel)
{
  int dir, chunk;
  if (dirsel < 0) { dir = blockIdx.x >> 2; chunk = blockIdx.x & 3; }
  else            { dir = dirsel;          chunk = blockIdx.x; }
  const int tid = threadIdx.x;
  const int gate_local = tid >> 1, khalf = tid & 1;
  const int gt = gate_local >> 6, hc = gate_local & 63;
  const int hcol = chunk * 64 + hc, grow = gt * 256 + hcol;

  __shared__ __align__(16) float g_lds[256];
  __shared__ __align__(16) float c_lds[64];
  __shared__ __align__(16) unsigned short h16[256];

  unsigned int w[64];
  {
    const uint4* wp = (const uint4*)(Wpk + ((size_t)((dir * 4 + chunk) * 512 + tid)) * 64);
#pragma unroll
    for (int q = 0; q < 16; ++q) {
      uint4 v = wp[q];
      w[4 * q + 0] = v.x; w[4 * q + 1] = v.y; w[4 * q + 2] = v.z; w[4 * q + 3] = v.w;
    }
  }
  const float bg = khalf ? 0.f : biasbuf[dir * 1024 + grow];
  const unsigned short* P = dir ? P_b : P_f;
  unsigned short* out = dir ? out_b : out_f;
  unsigned int* hxd = hx + dir * 512;

  if (tid < 64) c_lds[tid] = 0.f;
  __syncthreads();

  for (int t = 0; t < 4096; ++t) {
    // 1. poll & stage h^{(t)}  (slot t&1, exact tag == t; init state serves t=0)
    if (tid < 256) {
      unsigned int* src = hxd + ((t & 1) << 8) + tid;
      unsigned int v;
      do {
        v = __hip_atomic_load(src, __ATOMIC_RELAXED, __HIP_MEMORY_SCOPE_AGENT);
      } while ((v >> 16) != (unsigned)t);
      h16[tid] = (unsigned short)(v & 0xffffu);
    }
    __syncthreads();
    // 2. gate dot: each thread half a gate row (K=128)
    const int srow = dir ? (4095 - t) : t;
    float acc = 0.f;
    const uint4* hb = (const uint4*)(&h16[khalf * 128]);
#pragma unroll
    for (int q = 0; q < 16; ++q) {
      uint4 hv = hb[q];
      acc = fdot2u(w[4 * q + 0], hv.x, acc);
      acc = fdot2u(w[4 * q + 1], hv.y, acc);
      acc = fdot2u(w[4 * q + 2], hv.z, acc);
      acc = fdot2u(w[4 * q + 3], hv.w, acc);
    }
    acc += __shfl_xor(acc, 1);
    if (!khalf) g_lds[gate_local] = acc + bg + bf2f(P[(size_t)srow * 1024 + grow]);
    __syncthreads();
    // 3. cell + tagged publish (publish first to minimize cross-CU latency)
    if (tid < 64) {
      float gi = g_lds[tid], gf = g_lds[64 + tid], gg = g_lds[128 + tid], go = g_lds[192 + tid];
      if (badf(gi + gf + gg + go)) atomicOr(diag, 2);
      float cc = sigf(gf) * c_lds[tid] + sigf(gi) * tanh_f(gg);
      float hh = sigf(go) * tanh_f(cc);
      if (t < 4095) {
        unsigned int pk = ((unsigned)(t + 1) << 16) | (unsigned)f2h(hh);
        __hip_atomic_store(hxd + (((t + 1) & 1) << 8) + chunk * 64 + tid, pk,
                           __ATOMIC_RELAXED, __HIP_MEMORY_SCOPE_AGENT);
      }
      c_lds[tid] = cc;
      out[(size_t)srow * HHD + chunk * 64 + tid] = f2bf(hh);
    }
    __syncthreads();
  }
}

// ---------------- heads: logits + log_softmax -> f32 out
__global__ __launch_bounds__(128) void head_k(
    const unsigned short* __restrict__ out_f, const unsigned short* __restrict__ out_b,
    const float* __restrict__ Wpos, const float* __restrict__ bpos,
    const float* __restrict__ Wner, const float* __restrict__ bner,
    float* __restrict__ dout, int* __restrict__ diag)
{
  const int s = blockIdx.x, tid = threadIdx.x;
  __shared__ __align__(16) float xv[512];
#pragma unroll
  for (int i = 0; i < 4; ++i) {
    int k = tid * 4 + i;
    xv[k] = (k < 256) ? bf2f(out_f[(size_t)s * 256 + k])
                      : bf2f(out_b[(size_t)s * 256 + (k - 256)]);
  }
  __syncthreads();
  float logit = 0.f;
  const int j = tid;
  if (j < 96) {
    const float* wr = (j < 64) ? (Wpos + (size_t)j * 512)
                               : (Wner + (size_t)(j - 64) * 512);
    float b = (j < 64) ? bpos[j] : bner[j - 64];
    float acc = 0.f;
    for (int k = 0; k < 512; k += 4) {
      float4 wv = *(const float4*)(wr + k);
      acc += xv[k] * wv.x + xv[k + 1] * wv.y + xv[k + 2] * wv.z + xv[k + 3] * wv.w;
    }
    logit = acc + b;
    if (badf(logit)) { atomicOr(diag, 4); logit = 0.f; }
  }
  if (j < 64) {
    float m = logit;
    for (int o = 32; o >= 1; o >>= 1) m = fmaxf(m, __shfl_xor(m, o));
    float e = __expf(logit - m), sum = e;
    for (int o = 32; o >= 1; o >>= 1) sum += __shfl_xor(sum, o);
    float v = logit - m - logf(sum);
    if (!(v > -1e30f && v < 1e30f)) v = -111.f;
    dout[(size_t)s * 64 + j] = v;
  } else if (j < 96) {
    float m = logit;
    for (int o = 16; o >= 1; o >>= 1) m = fmaxf(m, __shfl_xor(m, o, 32));
    float e = __expf(logit - m), sum = e;
    for (int o = 16; o >= 1; o >>= 1) sum += __shfl_xor(sum, o, 32);
    float v = logit - m - logf(sum);
    if (!(v > -1e30f && v < 1e30f)) v = -111.f;
    dout[262144 + (size_t)s * 32 + (j - 64)] = v;
  }
}

// ---------------- diagnostics (silent when healthy)
__global__ void diag_k(const float* __restrict__ ce,
                       int* __restrict__ diag,
                       float* __restrict__ dout)
{
  int cnt = 0;
  for (int i = 0; i < 64; ++i) {
    float x = ce[i];
    if (x == x && fabsf(x) < 100.f) cnt++;
  }
  if (cnt < 48) diag[0] |= 8;
  int d = diag[0];
  if (d) dout[0] = 1000.f + 100.f * (float)d;
}

__global__ void wssmall_k(float* __restrict__ dout, int mb)
{
  dout[0] = 10000.f + (float)mb;
}

extern "C" void kernel_launch(void* const* d_in, const int* in_sizes, int n_in,
                              void* d_out, int out_size, void* d_ws, size_t ws_size,
                              hipStream_t stream) {
  const int*   word_seq  = (const int*)d_in[0];
  const int*   chars     = (const int*)d_in[1];
  const int*   char_lens = (const int*)d_in[2];
  const int*   feat_seq  = (const int*)d_in[3];
  const float* char_emb  = (const float*)d_in[4];
  const float* word_emb  = (const float*)d_in[5];
  const float* prefix_emb= (const float*)d_in[6];
  const float* Wih_c     = (const float*)d_in[7];
  const float* Whh_c     = (const float*)d_in[8];
  const float* bih_c     = (const float*)d_in[9];
  const float* bhh_c     = (const float*)d_in[10];
  const float* Wih_f     = (const float*)d_in[11];
  const float* Whh_f     = (const float*)d_in[12];
  const float* bih_f     = (const float*)d_in[13];
  const float* bhh_f     = (const float*)d_in[14];
  const float* Wih_b     = (const float*)d_in[15];
  const float* Whh_b     = (const float*)d_in[16];
  const float* bih_b     = (const float*)d_in[17];
  const float* bhh_b     = (const float*)d_in[18];
  const float* Wpos      = (const float*)d_in[19];
  const float* bpos      = (const float*)d_in[20];
  const float* Wner      = (const float*)d_in[21];
  const float* bner      = (const float*)d_in[22];
  float* dout = (float*)d_out;

  const size_t MB = 1048576;
  char* ws = (char*)d_ws;
  // small region
  int*            diag  = (int*)(ws + 512);          // 512 B
  unsigned int*   hx    = (unsigned int*)(ws + 1024);// 4 KB (2 dirs x 2 slots x 256 u32)
  float*          bias2 = (float*)(ws + 8192);       // 8 KB
  unsigned int*   Wpk   = (unsigned int*)(ws + 65536);// 1 MB
  // big region (phase-overlapped)
  unsigned short* hA    = (unsigned short*)(ws + 2 * MB);   // 4 MB [4096,512] bf16
  unsigned short* hB    = (unsigned short*)(ws + 6 * MB);   // 4 MB
  unsigned short* xUb   = (unsigned short*)(ws + 10 * MB);  // 2 MB [512,2048] bf16
  unsigned short* cb    = (unsigned short*)(ws + 12 * MB);  // 4 MB [4096,512] bf16

  const size_t NEED_A2 = 22 * MB;  // P_f 6..14, P_b 14..22 (both scans in parallel)
  const size_t NEED_B  = 16 * MB;  // sequential dir scans, shared P buffer
  unsigned short* P_f;
  unsigned short* P_b;
  unsigned short* out_f;
  unsigned short* out_b;
  int layoutA;
  if (ws_size >= NEED_A2) {
    layoutA = 1;
    P_f   = (unsigned short*)(ws + 6 * MB);    // over dead hB/xUb
    P_b   = (unsigned short*)(ws + 14 * MB);   // over dead cb + fresh
    out_f = (unsigned short*)(ws + 2 * MB);    // over dead hA
    out_b = (unsigned short*)(ws + 4 * MB);
  } else if (ws_size >= NEED_B) {
    layoutA = 0;
    P_f   = (unsigned short*)(ws + 6 * MB);
    P_b   = (unsigned short*)(ws + 6 * MB);
    out_f = (unsigned short*)(ws + 14 * MB);
    out_b = (unsigned short*)(ws + 2 * MB);
  } else {
    wssmall_k<<<1, 1, 0, stream>>>(dout, (int)(ws_size >> 20));
    return;
  }

  prep_xu_k<<<(512 * 2048) / 256, 256, 0, stream>>>(char_emb, Wih_c, bih_c, bhh_c, xUb);
  prep_h0c0_k<<<(4096 * 512) / 256, 256, 0, stream>>>(prefix_emb, feat_seq, hA, cb);
  prep_scanw_k<<<(2 * 4 * 512 * 64) / 256, 256, 0, stream>>>(
      Whh_f, Whh_b, bih_f, bhh_f, bih_b, bhh_b, Wpk, bias2, hx, diag);

  unsigned short* hcur = hA;
  unsigned short* hnxt = hB;
  for (int t = 0; t < 16; ++t) {
    gemm_char_k<<<dim3(16, 32), 256, 0, stream>>>(
        hcur, Whh_c, xUb, chars, char_lens, t, hnxt, cb, diag);
    unsigned short* tmp = hcur; hcur = hnxt; hnxt = tmp;
  }
  // after 16 swaps, final char features are in hA (hcur == hA)

  if (layoutA) {
    gemm_gather_nt_k<<<dim3(8, 32), 256, 0, stream>>>(word_emb, word_seq, hcur, Wih_f, P_f);
    gemm_gather_nt_k<<<dim3(8, 32), 256, 0, stream>>>(word_emb, word_seq, hcur, Wih_b, P_b);
    scan_k<<<8, 512, 0, stream>>>(P_f, P_b, Wpk, bias2, out_f, out_b, hx, diag, -1);
  } else {
    gemm_gather_nt_k<<<dim3(8, 32), 256, 0, stream>>>(word_emb, word_seq, hcur, Wih_f, P_f);
    scan_k<<<4, 512, 0, stream>>>(P_f, P_b, Wpk, bias2, out_f, out_b, hx, diag, 0);
    gemm_gather_nt_k<<<dim3(8, 32), 256, 0, stream>>>(word_emb, word_seq, hcur, Wih_b, P_b);
    scan_k<<<4, 512, 0, stream>>>(P_f, P_b, Wpk, bias2, out_f, out_b, hx, diag, 1);
  }

  head_k<<<4096, 128, 0, stream>>>(out_f, out_b, Wpos, bpos, Wner, bner, dout, diag);

  diag_k<<<1, 1, 0, stream>>>(char_emb, diag, dout);
}